// Round 1
// baseline (511.222 us; speedup 1.0000x reference)
//
#include <hip/hip_runtime.h>
#include <hip/hip_bf16.h>

#define B_ 64
#define N_ 2048
#define E_ 16384
#define F_ 32
#define H_ 64
#define K_ 8
#define C_ 16
#define G_ 64
#define CAP 192   // linc row nnz capacity (mean 64, Poisson tail @192 ~ 0)

// ---------------- Kernel A: edge MLP -> w[E,K] ----------------
__global__ __launch_bounds__(256) void edge_mlp_k(
    const float* __restrict__ ef, const float* __restrict__ w1,
    const float* __restrict__ b1, const float* __restrict__ w2,
    const float* __restrict__ b2, float* __restrict__ w_out) {
  __shared__ float s_w1[H_*F_];
  __shared__ float s_w2[K_*H_];
  __shared__ float s_b1[H_];
  __shared__ float s_b2[K_];
  int t = threadIdx.x;
  for (int i = t; i < H_*F_; i += 256) s_w1[i] = w1[i];
  for (int i = t; i < K_*H_; i += 256) s_w2[i] = w2[i];
  if (t < H_) s_b1[t] = b1[t];
  if (t < K_) s_b2[t] = b2[t];
  __syncthreads();
  int e = blockIdx.x*256 + t;
  float efr[F_];
  const float4* efp = (const float4*)(ef + (size_t)e*F_);
  #pragma unroll
  for (int f4 = 0; f4 < F_/4; f4++) {
    float4 v = efp[f4];
    efr[f4*4+0]=v.x; efr[f4*4+1]=v.y; efr[f4*4+2]=v.z; efr[f4*4+3]=v.w;
  }
  float acc[K_];
  #pragma unroll
  for (int k = 0; k < K_; k++) acc[k] = s_b2[k];
  #pragma unroll 4
  for (int h = 0; h < H_; h++) {
    float hv = s_b1[h];
    #pragma unroll
    for (int f = 0; f < F_; f++) hv = fmaf(efr[f], s_w1[h*F_+f], hv);
    hv = fmaxf(hv, 0.f);
    #pragma unroll
    for (int k = 0; k < K_; k++) acc[k] = fmaf(hv, s_w2[k*H_+h], acc[k]);
  }
  #pragma unroll
  for (int k = 0; k < K_; k++) w_out[(size_t)e*K_ + k] = acc[k];
}

// ---------------- Kernel B: z[e][b*16+c] = sum_{n: rinc[e,n]!=0} x[b,n,c] ----------------
__global__ __launch_bounds__(256) void gather_z_k(
    const float* __restrict__ rinc, const float* __restrict__ x,
    __hip_bfloat16* __restrict__ z) {
  __shared__ int s_idx[64];   // rinc row nnz: mean 8
  __shared__ int s_cnt;
  int t = threadIdx.x;
  int e = blockIdx.x;
  if (t == 0) s_cnt = 0;
  __syncthreads();
  const float4* row = (const float4*)(rinc + (size_t)e*N_);
  #pragma unroll
  for (int j = 0; j < N_/4/256; j++) {       // 2 float4 per thread
    int i = t + 256*j;
    float4 v = row[i];
    if (v.x != 0.f) { int p = atomicAdd(&s_cnt,1); if (p<64) s_idx[p]=i*4+0; }
    if (v.y != 0.f) { int p = atomicAdd(&s_cnt,1); if (p<64) s_idx[p]=i*4+1; }
    if (v.z != 0.f) { int p = atomicAdd(&s_cnt,1); if (p<64) s_idx[p]=i*4+2; }
    if (v.w != 0.f) { int p = atomicAdd(&s_cnt,1); if (p<64) s_idx[p]=i*4+3; }
  }
  __syncthreads();
  int cnt = min(s_cnt, 64);
  #pragma unroll
  for (int j = 0; j < 4; j++) {
    int bc = t + 256*j;                       // bc = b*16+c
    int b = bc >> 4, c = bc & 15;
    float acc = 0.f;
    for (int i = 0; i < cnt; i++) {
      int n = s_idx[i];
      acc += x[(size_t)b*(N_*C_) + n*C_ + c];
    }
    z[(size_t)e*(B_*C_) + bc] = __float2bfloat16(acc);
  }
}

// ---------------- Kernel C: per-node y accumulate + fused output GEMM ----------------
__global__ __launch_bounds__(256) void node_out_k(
    const float* __restrict__ linc, const __hip_bfloat16* __restrict__ z,
    const float* __restrict__ w, const float* __restrict__ gcw,
    const float* __restrict__ gcb, float* __restrict__ out) {
  const int YLD = C_*K_ + 4;                  // 132: pad kills epilogue bank conflicts
  __shared__ float s_y[B_*YLD];               // 33.8 KB
  __shared__ __hip_bfloat16 s_gcwT[C_*K_*G_]; // [ck][g], 16 KB
  __shared__ int   s_idx[CAP];
  __shared__ float s_w[CAP*K_];
  __shared__ int   s_cnt;
  int t = threadIdx.x;
  int n = blockIdx.x;
  if (t == 0) s_cnt = 0;
  __syncthreads();

  // stage gcw transposed (bf16)
  for (int i = t; i < G_*C_*K_; i += 256) {
    int g = i >> 7, ck = i & 127;
    s_gcwT[ck*G_ + g] = __float2bfloat16(gcw[i]);
  }
  // scan linc row n (64 KB, float4-coalesced)
  const float4* row = (const float4*)(linc + (size_t)n*E_);
  #pragma unroll
  for (int j = 0; j < E_/4/256; j++) {        // 16 float4 per thread
    int i = t + 256*j;
    float4 v = row[i];
    if (v.x != 0.f) { int p = atomicAdd(&s_cnt,1); if (p<CAP) s_idx[p]=i*4+0; }
    if (v.y != 0.f) { int p = atomicAdd(&s_cnt,1); if (p<CAP) s_idx[p]=i*4+1; }
    if (v.z != 0.f) { int p = atomicAdd(&s_cnt,1); if (p<CAP) s_idx[p]=i*4+2; }
    if (v.w != 0.f) { int p = atomicAdd(&s_cnt,1); if (p<CAP) s_idx[p]=i*4+3; }
  }
  __syncthreads();
  int cnt = min(s_cnt, CAP);
  // stage per-edge kernel weights
  for (int i = t; i < cnt*K_; i += 256) {
    int ii = i >> 3, k = i & 7;
    s_w[i] = w[(size_t)s_idx[ii]*K_ + k];
  }
  __syncthreads();

  // accumulate y in registers: thread owns bc = t+256j, 8 k's each
  float acc[4][K_];
  #pragma unroll
  for (int j = 0; j < 4; j++)
    #pragma unroll
    for (int k = 0; k < K_; k++) acc[j][k] = 0.f;
  for (int i = 0; i < cnt; i++) {
    int e = s_idx[i];
    float we[K_];
    #pragma unroll
    for (int k = 0; k < K_; k++) we[k] = s_w[i*K_ + k];
    #pragma unroll
    for (int j = 0; j < 4; j++) {
      int bc = t + 256*j;
      float zv = __bfloat162float(z[(size_t)e*(B_*C_) + bc]);
      #pragma unroll
      for (int k = 0; k < K_; k++) acc[j][k] = fmaf(zv, we[k], acc[j][k]);
    }
  }
  // spill y to LDS: y[b][c*K+k]
  #pragma unroll
  for (int j = 0; j < 4; j++) {
    int bc = t + 256*j;
    int b = bc >> 4, c = bc & 15;
    #pragma unroll
    for (int k = 0; k < K_; k++) s_y[b*YLD + c*K_ + k] = acc[j][k];
  }
  __syncthreads();

  // epilogue GEMM: out[b, n, g] = relu(y[b,:] . gcw[g,:] + gcb[g]); 4x4 tile/thread
  int tg = t & 15, tb = t >> 4;
  int g0 = tg*4, b0 = tb*4;
  float o[4][4];
  #pragma unroll
  for (int i = 0; i < 4; i++)
    #pragma unroll
    for (int jj = 0; jj < 4; jj++) o[i][jj] = 0.f;
  for (int ck = 0; ck < C_*K_; ck += 4) {
    float yv[4][4];
    #pragma unroll
    for (int i = 0; i < 4; i++) {
      const float4 yq = *(const float4*)&s_y[(b0+i)*YLD + ck];
      yv[i][0]=yq.x; yv[i][1]=yq.y; yv[i][2]=yq.z; yv[i][3]=yq.w;
    }
    float gv[4][4];
    #pragma unroll
    for (int kk = 0; kk < 4; kk++) {
      const __hip_bfloat162* gp = (const __hip_bfloat162*)&s_gcwT[(ck+kk)*G_ + g0];
      float2 a = __bfloat1622float2(gp[0]);
      float2 b2v = __bfloat1622float2(gp[1]);
      gv[kk][0]=a.x; gv[kk][1]=a.y; gv[kk][2]=b2v.x; gv[kk][3]=b2v.y;
    }
    #pragma unroll
    for (int kk = 0; kk < 4; kk++)
      #pragma unroll
      for (int i = 0; i < 4; i++)
        #pragma unroll
        for (int jj = 0; jj < 4; jj++)
          o[i][jj] = fmaf(yv[i][kk], gv[kk][jj], o[i][jj]);
  }
  float bias[4];
  #pragma unroll
  for (int jj = 0; jj < 4; jj++) bias[jj] = gcb[g0+jj];
  #pragma unroll
  for (int i = 0; i < 4; i++) {
    int b = b0 + i;
    float4 res;
    res.x = fmaxf(o[i][0]+bias[0], 0.f);
    res.y = fmaxf(o[i][1]+bias[1], 0.f);
    res.z = fmaxf(o[i][2]+bias[2], 0.f);
    res.w = fmaxf(o[i][3]+bias[3], 0.f);
    *(float4*)&out[(size_t)b*(N_*G_) + (size_t)n*G_ + g0] = res;
  }
}

extern "C" void kernel_launch(void* const* d_in, const int* in_sizes, int n_in,
                              void* d_out, int out_size, void* d_ws, size_t ws_size,
                              hipStream_t stream) {
  const float* x    = (const float*)d_in[0];
  const float* linc = (const float*)d_in[1];
  const float* rinc = (const float*)d_in[2];
  const float* ef   = (const float*)d_in[3];
  const float* w1   = (const float*)d_in[4];
  const float* b1   = (const float*)d_in[5];
  const float* w2   = (const float*)d_in[6];
  const float* b2   = (const float*)d_in[7];
  const float* gcw  = (const float*)d_in[8];
  const float* gcb  = (const float*)d_in[9];
  float* out = (float*)d_out;

  float* w_e = (float*)d_ws;                                   // E*K f32 = 512 KB
  __hip_bfloat16* z = (__hip_bfloat16*)((char*)d_ws + (size_t)E_*K_*sizeof(float)); // E*1024 bf16 = 33.5 MB

  edge_mlp_k<<<E_/256, 256, 0, stream>>>(ef, w1, b1, w2, b2, w_e);
  gather_z_k<<<E_, 256, 0, stream>>>(rinc, x, z);
  node_out_k<<<N_, 256, 0, stream>>>(linc, z, w_e, gcw, gcb, out);
}

// Round 2
// 416.237 us; speedup vs baseline: 1.2282x; 1.2282x over previous
//
#include <hip/hip_runtime.h>
#include <hip/hip_bf16.h>

#define B_ 64
#define N_ 2048
#define E_ 16384
#define F_ 32
#define H_ 64
#define K_ 8
#define C_ 16
#define G_ 64
#define CK 128        // C_*K_
#define CAP 128       // linc row nnz capacity (Binomial mean 64, sd 8 -> mean+8sd)
#define YLD 136       // bf16 row stride for s_y / s_gcwB (pad 8: 16B-aligned rows, 2-way banks)

typedef __attribute__((ext_vector_type(8))) short bf16x8;
typedef __attribute__((ext_vector_type(4))) float f32x4;

__device__ inline float bf2f(unsigned short u) {
  union { unsigned int i; float f; } v; v.i = ((unsigned int)u) << 16; return v.f;
}
__device__ inline unsigned short f2bf(float f) {
  union { float f; unsigned int i; } v; v.f = f;
  unsigned int x = v.i;
  return (unsigned short)((x + 0x7fffu + ((x >> 16) & 1u)) >> 16);
}

// ---------------- Kernel A: edge MLP -> w[E,K] ----------------
__global__ __launch_bounds__(256) void edge_mlp_k(
    const float* __restrict__ ef, const float* __restrict__ w1,
    const float* __restrict__ b1, const float* __restrict__ w2,
    const float* __restrict__ b2, float* __restrict__ w_out) {
  __shared__ float s_w1[H_*F_];
  __shared__ float s_w2[K_*H_];
  __shared__ float s_b1[H_];
  __shared__ float s_b2[K_];
  int t = threadIdx.x;
  for (int i = t; i < H_*F_; i += 256) s_w1[i] = w1[i];
  for (int i = t; i < K_*H_; i += 256) s_w2[i] = w2[i];
  if (t < H_) s_b1[t] = b1[t];
  if (t < K_) s_b2[t] = b2[t];
  __syncthreads();
  int e = blockIdx.x*256 + t;
  float efr[F_];
  const float4* efp = (const float4*)(ef + (size_t)e*F_);
  #pragma unroll
  for (int f4 = 0; f4 < F_/4; f4++) {
    float4 v = efp[f4];
    efr[f4*4+0]=v.x; efr[f4*4+1]=v.y; efr[f4*4+2]=v.z; efr[f4*4+3]=v.w;
  }
  float acc[K_];
  #pragma unroll
  for (int k = 0; k < K_; k++) acc[k] = s_b2[k];
  #pragma unroll 4
  for (int h = 0; h < H_; h++) {
    float hv = s_b1[h];
    #pragma unroll
    for (int f = 0; f < F_; f++) hv = fmaf(efr[f], s_w1[h*F_+f], hv);
    hv = fmaxf(hv, 0.f);
    #pragma unroll
    for (int k = 0; k < K_; k++) acc[k] = fmaf(hv, s_w2[k*H_+h], acc[k]);
  }
  #pragma unroll
  for (int k = 0; k < K_; k++) w_out[(size_t)e*K_ + k] = acc[k];
}

// ------- Kernel B: z[e][bc] (bf16) = sum_{n: rinc[e,n]!=0} x[b,n,c], bc = b*16+c -------
__global__ __launch_bounds__(256) void gather_z_k(
    const float* __restrict__ rinc, const float* __restrict__ x,
    unsigned short* __restrict__ z) {
  __shared__ int s_idx[64];   // rinc row nnz: mean 8, sd 2.8
  __shared__ int s_cnt;
  int t = threadIdx.x;
  int e = blockIdx.x;
  if (t == 0) s_cnt = 0;
  __syncthreads();
  const float4* row = (const float4*)(rinc + (size_t)e*N_);
  #pragma unroll
  for (int j = 0; j < N_/4/256; j++) {       // 2 float4 per thread
    int i = t + 256*j;
    float4 v = row[i];
    if (v.x != 0.f) { int p = atomicAdd(&s_cnt,1); if (p<64) s_idx[p]=i*4+0; }
    if (v.y != 0.f) { int p = atomicAdd(&s_cnt,1); if (p<64) s_idx[p]=i*4+1; }
    if (v.z != 0.f) { int p = atomicAdd(&s_cnt,1); if (p<64) s_idx[p]=i*4+2; }
    if (v.w != 0.f) { int p = atomicAdd(&s_cnt,1); if (p<64) s_idx[p]=i*4+3; }
  }
  __syncthreads();
  int cnt = min(s_cnt, 64);
  // thread t owns bc = 4t..4t+3 -> b = t>>2, c0 = (t&3)*4 : one float4 x-load per nnz
  int b = t >> 2, c0 = (t & 3) * 4;
  const float* xb = x + (size_t)b*(N_*C_) + c0;
  float4 acc = make_float4(0.f, 0.f, 0.f, 0.f);
  for (int i = 0; i < cnt; i++) {
    int n = s_idx[i];
    float4 xv = *(const float4*)(xb + (size_t)n*C_);
    acc.x += xv.x; acc.y += xv.y; acc.z += xv.z; acc.w += xv.w;
  }
  ushort4 zu;
  zu.x = f2bf(acc.x); zu.y = f2bf(acc.y); zu.z = f2bf(acc.z); zu.w = f2bf(acc.w);
  *(ushort4*)&z[(size_t)e*(B_*C_) + 4*t] = zu;
}

// ------- Kernel C: per-node y accumulate (VALU) + MFMA output GEMM -------
__global__ __launch_bounds__(256, 4) void node_out_k(
    const float* __restrict__ linc, const unsigned short* __restrict__ z,
    const float* __restrict__ w, const float* __restrict__ gcw,
    const float* __restrict__ gcb, float* __restrict__ out) {
  __shared__ unsigned short s_y[B_*YLD];     // y as bf16, [b][ck], 17.4 KB
  __shared__ unsigned short s_gcwB[G_*YLD];  // gcw as bf16, [g][ck], 17.4 KB
  __shared__ float s_gcb[G_];
  __shared__ int   s_idx[CAP];
  __shared__ float s_w[CAP*K_];
  __shared__ int   s_cnt;
  int t = threadIdx.x;
  int n = blockIdx.x;
  if (t == 0) s_cnt = 0;
  __syncthreads();

  // stage gcw (bf16, [g][ck]) and gcb
  for (int i = t; i < G_*CK; i += 256) {
    int g = i >> 7, ck = i & (CK-1);
    s_gcwB[g*YLD + ck] = f2bf(gcw[i]);
  }
  if (t < G_) s_gcb[t] = gcb[t];

  // scan linc row n (64 KB, float4-coalesced)
  const float4* row = (const float4*)(linc + (size_t)n*E_);
  #pragma unroll
  for (int j = 0; j < E_/4/256; j++) {        // 16 float4 per thread
    int i = t + 256*j;
    float4 v = row[i];
    if (v.x != 0.f) { int p = atomicAdd(&s_cnt,1); if (p<CAP) s_idx[p]=i*4+0; }
    if (v.y != 0.f) { int p = atomicAdd(&s_cnt,1); if (p<CAP) s_idx[p]=i*4+1; }
    if (v.z != 0.f) { int p = atomicAdd(&s_cnt,1); if (p<CAP) s_idx[p]=i*4+2; }
    if (v.w != 0.f) { int p = atomicAdd(&s_cnt,1); if (p<CAP) s_idx[p]=i*4+3; }
  }
  __syncthreads();
  int cnt = min(s_cnt, CAP);
  for (int i = t; i < cnt*K_; i += 256) {
    int ii = i >> 3, k = i & 7;
    s_w[i] = w[(size_t)s_idx[ii]*K_ + k];
  }
  __syncthreads();

  // stage 1: y accumulate. Thread owns bc = 4t..4t+3 (b = t>>2, c0 = (t&3)*4), all 8 k.
  float acc[4][K_];
  #pragma unroll
  for (int j = 0; j < 4; j++)
    #pragma unroll
    for (int k = 0; k < K_; k++) acc[j][k] = 0.f;
  const unsigned short* zt = z + 4*t;
  for (int i = 0; i < cnt; i++) {
    int e = s_idx[i];
    const float4* wp = (const float4*)&s_w[i*K_];
    float4 w0 = wp[0], w1v = wp[1];
    float we[K_] = {w0.x, w0.y, w0.z, w0.w, w1v.x, w1v.y, w1v.z, w1v.w};
    ushort4 zu = *(const ushort4*)(zt + (size_t)e*(B_*C_));
    float zv[4] = {bf2f(zu.x), bf2f(zu.y), bf2f(zu.z), bf2f(zu.w)};
    #pragma unroll
    for (int j = 0; j < 4; j++)
      #pragma unroll
      for (int k = 0; k < K_; k++) acc[j][k] = fmaf(zv[j], we[k], acc[j][k]);
  }
  // spill y -> LDS bf16: thread covers 32 consecutive ck at row b (4x b128 stores)
  {
    int b = t >> 2, ckb = (t & 3) * 32;
    #pragma unroll
    for (int j = 0; j < 4; j++) {
      ushort4 lo, hi;
      lo.x = f2bf(acc[j][0]); lo.y = f2bf(acc[j][1]); lo.z = f2bf(acc[j][2]); lo.w = f2bf(acc[j][3]);
      hi.x = f2bf(acc[j][4]); hi.y = f2bf(acc[j][5]); hi.z = f2bf(acc[j][6]); hi.w = f2bf(acc[j][7]);
      *(ushort4*)&s_y[b*YLD + ckb + 8*j]     = lo;
      *(ushort4*)&s_y[b*YLD + ckb + 8*j + 4] = hi;
    }
  }
  __syncthreads();

  // stage 2: out[b, n, g] = relu(y[b,:] . gcw[g,:] + gcb[g]) via MFMA 16x16x32 bf16.
  // Wave wv does b-rows [16wv,16wv+16); 4 g-frags of 16; K = 128 in 4 steps.
  {
    int wv = t >> 6, lane = t & 63;
    int m = lane & 15, q = lane >> 4;
    f32x4 cf0 = {0.f,0.f,0.f,0.f}, cf1 = cf0, cf2 = cf0, cf3 = cf0;
    #pragma unroll
    for (int ks = 0; ks < 4; ks++) {
      bf16x8 a = *(const bf16x8*)&s_y[(16*wv + m)*YLD + 32*ks + 8*q];
      bf16x8 b0 = *(const bf16x8*)&s_gcwB[(m     )*YLD + 32*ks + 8*q];
      bf16x8 b1 = *(const bf16x8*)&s_gcwB[(16 + m)*YLD + 32*ks + 8*q];
      bf16x8 b2 = *(const bf16x8*)&s_gcwB[(32 + m)*YLD + 32*ks + 8*q];
      bf16x8 b3 = *(const bf16x8*)&s_gcwB[(48 + m)*YLD + 32*ks + 8*q];
      cf0 = __builtin_amdgcn_mfma_f32_16x16x32_bf16(a, b0, cf0, 0, 0, 0);
      cf1 = __builtin_amdgcn_mfma_f32_16x16x32_bf16(a, b1, cf1, 0, 0, 0);
      cf2 = __builtin_amdgcn_mfma_f32_16x16x32_bf16(a, b2, cf2, 0, 0, 0);
      cf3 = __builtin_amdgcn_mfma_f32_16x16x32_bf16(a, b3, cf3, 0, 0, 0);
    }
    // C/D layout: col = lane&15 (g within frag), row = q*4 + r (b within 16)
    float* ob = out + (size_t)n*G_;
    #pragma unroll
    for (int r = 0; r < 4; r++) {
      int b = 16*wv + 4*q + r;
      float* op = ob + (size_t)b*(N_*G_);
      float v0 = fmaxf(cf0[r] + s_gcb[m],      0.f);
      float v1 = fmaxf(cf1[r] + s_gcb[16 + m], 0.f);
      float v2 = fmaxf(cf2[r] + s_gcb[32 + m], 0.f);
      float v3 = fmaxf(cf3[r] + s_gcb[48 + m], 0.f);
      op[m]      = v0;
      op[16 + m] = v1;
      op[32 + m] = v2;
      op[48 + m] = v3;
    }
  }
}

extern "C" void kernel_launch(void* const* d_in, const int* in_sizes, int n_in,
                              void* d_out, int out_size, void* d_ws, size_t ws_size,
                              hipStream_t stream) {
  const float* x    = (const float*)d_in[0];
  const float* linc = (const float*)d_in[1];
  const float* rinc = (const float*)d_in[2];
  const float* ef   = (const float*)d_in[3];
  const float* w1   = (const float*)d_in[4];
  const float* b1   = (const float*)d_in[5];
  const float* w2   = (const float*)d_in[6];
  const float* b2   = (const float*)d_in[7];
  const float* gcw  = (const float*)d_in[8];
  const float* gcb  = (const float*)d_in[9];
  float* out = (float*)d_out;

  float* w_e = (float*)d_ws;                                   // E*K f32 = 512 KB
  unsigned short* z = (unsigned short*)((char*)d_ws + (size_t)E_*K_*sizeof(float)); // E*1024 bf16

  edge_mlp_k<<<E_/256, 256, 0, stream>>>(ef, w1, b1, w2, b2, w_e);
  gather_z_k<<<E_, 256, 0, stream>>>(rinc, x, z);
  node_out_k<<<N_, 256, 0, stream>>>(linc, z, w_e, gcw, gcb, out);
}

// Round 3
// 372.992 us; speedup vs baseline: 1.3706x; 1.1159x over previous
//
#include <hip/hip_runtime.h>
#include <hip/hip_bf16.h>

#define B_ 64
#define N_ 2048
#define E_ 16384
#define F_ 32
#define H_ 64
#define K_ 8
#define C_ 16
#define G_ 64
#define CK 128        // C_*K_
#define CAP 128       // linc row nnz capacity (Binomial mean 64, sd 8 -> mean+8sd)
#define YLD 136       // bf16 row stride for s_y / s_gcwB (pad 8: 16B-aligned rows, 2-way banks)
#define BC 1024       // B_*C_

typedef __attribute__((ext_vector_type(8))) short bf16x8;
typedef __attribute__((ext_vector_type(4))) float f32x4;

__device__ inline float bf2f(unsigned short u) {
  union { unsigned int i; float f; } v; v.i = ((unsigned int)u) << 16; return v.f;
}
__device__ inline unsigned short f2bf(float f) {
  union { float f; unsigned int i; } v; v.f = f;
  unsigned int x = v.i;
  return (unsigned short)((x + 0x7fffu + ((x >> 16) & 1u)) >> 16);
}

// ---------------- Kernel X: transpose x[b,n,c] -> x_t[n][b*16+c] (bf16) ----------------
__global__ __launch_bounds__(256) void xpose_k(
    const float* __restrict__ x, unsigned short* __restrict__ x_t) {
  int t = threadIdx.x;
  int n = blockIdx.x;
  int b = t >> 2, c0 = (t & 3) * 4;
  float4 xv = *(const float4*)(x + (size_t)b*(N_*C_) + (size_t)n*C_ + c0);
  ushort4 o;
  o.x = f2bf(xv.x); o.y = f2bf(xv.y); o.z = f2bf(xv.z); o.w = f2bf(xv.w);
  *(ushort4*)&x_t[(size_t)n*BC + 4*t] = o;
}

// ---------------- Kernel A: edge MLP -> w[E,K] ----------------
__global__ __launch_bounds__(256) void edge_mlp_k(
    const float* __restrict__ ef, const float* __restrict__ w1,
    const float* __restrict__ b1, const float* __restrict__ w2,
    const float* __restrict__ b2, float* __restrict__ w_out) {
  __shared__ float s_w1[H_*F_];
  __shared__ float s_w2[K_*H_];
  __shared__ float s_b1[H_];
  __shared__ float s_b2[K_];
  int t = threadIdx.x;
  for (int i = t; i < H_*F_; i += 256) s_w1[i] = w1[i];
  for (int i = t; i < K_*H_; i += 256) s_w2[i] = w2[i];
  if (t < H_) s_b1[t] = b1[t];
  if (t < K_) s_b2[t] = b2[t];
  __syncthreads();
  int e = blockIdx.x*256 + t;
  float efr[F_];
  const float4* efp = (const float4*)(ef + (size_t)e*F_);
  #pragma unroll
  for (int f4 = 0; f4 < F_/4; f4++) {
    float4 v = efp[f4];
    efr[f4*4+0]=v.x; efr[f4*4+1]=v.y; efr[f4*4+2]=v.z; efr[f4*4+3]=v.w;
  }
  float acc[K_];
  #pragma unroll
  for (int k = 0; k < K_; k++) acc[k] = s_b2[k];
  #pragma unroll 4
  for (int h = 0; h < H_; h++) {
    float hv = s_b1[h];
    #pragma unroll
    for (int f = 0; f < F_; f++) hv = fmaf(efr[f], s_w1[h*F_+f], hv);
    hv = fmaxf(hv, 0.f);
    #pragma unroll
    for (int k = 0; k < K_; k++) acc[k] = fmaf(hv, s_w2[k*H_+h], acc[k]);
  }
  #pragma unroll
  for (int k = 0; k < K_; k++) w_out[(size_t)e*K_ + k] = acc[k];
}

// ------- Kernel B: z[e][bc] (bf16) = sum_{n: rinc[e,n]!=0} x_t[n][bc] -------
__global__ __launch_bounds__(256) void gather_z_k(
    const float* __restrict__ rinc, const unsigned short* __restrict__ x_t,
    unsigned short* __restrict__ z) {
  __shared__ int s_idx[64];   // rinc row nnz: mean 8, sd 2.8
  __shared__ int s_cnt;
  int t = threadIdx.x;
  int e = blockIdx.x;
  if (t == 0) s_cnt = 0;
  __syncthreads();
  const float4* row = (const float4*)(rinc + (size_t)e*N_);
  #pragma unroll
  for (int j = 0; j < N_/4/256; j++) {       // 2 float4 per thread
    int i = t + 256*j;
    float4 v = row[i];
    if (v.x != 0.f) { int p = atomicAdd(&s_cnt,1); if (p<64) s_idx[p]=i*4+0; }
    if (v.y != 0.f) { int p = atomicAdd(&s_cnt,1); if (p<64) s_idx[p]=i*4+1; }
    if (v.z != 0.f) { int p = atomicAdd(&s_cnt,1); if (p<64) s_idx[p]=i*4+2; }
    if (v.w != 0.f) { int p = atomicAdd(&s_cnt,1); if (p<64) s_idx[p]=i*4+3; }
  }
  __syncthreads();
  int cnt = min(s_cnt, 64);
  // thread t owns bc = 4t..4t+3; per nnz the block reads one contiguous 2KB x_t row
  const unsigned short* xt = x_t + 4*t;
  float4 acc = make_float4(0.f, 0.f, 0.f, 0.f);
  for (int i = 0; i < cnt; i++) {
    int n = s_idx[i];
    ushort4 xv = *(const ushort4*)(xt + (size_t)n*BC);
    acc.x += bf2f(xv.x); acc.y += bf2f(xv.y); acc.z += bf2f(xv.z); acc.w += bf2f(xv.w);
  }
  ushort4 zu;
  zu.x = f2bf(acc.x); zu.y = f2bf(acc.y); zu.z = f2bf(acc.z); zu.w = f2bf(acc.w);
  *(ushort4*)&z[(size_t)e*BC + 4*t] = zu;
}

// ------- Kernel C: per-node y accumulate (VALU) + MFMA output GEMM -------
__global__ __launch_bounds__(256, 4) void node_out_k(
    const float* __restrict__ linc, const unsigned short* __restrict__ z,
    const float* __restrict__ w, const float* __restrict__ gcw,
    const float* __restrict__ gcb, float* __restrict__ out) {
  __shared__ unsigned short s_y[B_*YLD];     // y as bf16, [b][ck], 17.4 KB
  __shared__ unsigned short s_gcwB[G_*YLD];  // gcw as bf16, [g][ck], 17.4 KB
  __shared__ float s_gcb[G_];
  __shared__ int   s_idx[CAP];
  __shared__ float s_w[CAP*K_];
  __shared__ int   s_cnt;
  int t = threadIdx.x;
  int n = blockIdx.x;
  if (t == 0) s_cnt = 0;
  __syncthreads();

  // stage gcw (bf16, [g][ck]) and gcb
  for (int i = t; i < G_*CK; i += 256) {
    int g = i >> 7, ck = i & (CK-1);
    s_gcwB[g*YLD + ck] = f2bf(gcw[i]);
  }
  if (t < G_) s_gcb[t] = gcb[t];

  // scan linc row n (64 KB, float4-coalesced)
  const float4* row = (const float4*)(linc + (size_t)n*E_);
  #pragma unroll
  for (int j = 0; j < E_/4/256; j++) {        // 16 float4 per thread
    int i = t + 256*j;
    float4 v = row[i];
    if (v.x != 0.f) { int p = atomicAdd(&s_cnt,1); if (p<CAP) s_idx[p]=i*4+0; }
    if (v.y != 0.f) { int p = atomicAdd(&s_cnt,1); if (p<CAP) s_idx[p]=i*4+1; }
    if (v.z != 0.f) { int p = atomicAdd(&s_cnt,1); if (p<CAP) s_idx[p]=i*4+2; }
    if (v.w != 0.f) { int p = atomicAdd(&s_cnt,1); if (p<CAP) s_idx[p]=i*4+3; }
  }
  __syncthreads();
  int cnt = min(s_cnt, CAP);
  for (int i = t; i < cnt*K_; i += 256) {
    int ii = i >> 3, k = i & 7;
    s_w[i] = w[(size_t)s_idx[ii]*K_ + k];
  }
  __syncthreads();

  // stage 1: y accumulate. Thread owns bc = 4t..4t+3 (b = t>>2, c0 = (t&3)*4), all 8 k.
  float acc[4][K_];
  #pragma unroll
  for (int j = 0; j < 4; j++)
    #pragma unroll
    for (int k = 0; k < K_; k++) acc[j][k] = 0.f;
  const unsigned short* zt = z + 4*t;
  for (int i = 0; i < cnt; i++) {
    int e = s_idx[i];
    const float4* wp = (const float4*)&s_w[i*K_];
    float4 w0 = wp[0], w1v = wp[1];
    float we[K_] = {w0.x, w0.y, w0.z, w0.w, w1v.x, w1v.y, w1v.z, w1v.w};
    ushort4 zu = *(const ushort4*)(zt + (size_t)e*BC);
    float zv[4] = {bf2f(zu.x), bf2f(zu.y), bf2f(zu.z), bf2f(zu.w)};
    #pragma unroll
    for (int j = 0; j < 4; j++)
      #pragma unroll
      for (int k = 0; k < K_; k++) acc[j][k] = fmaf(zv[j], we[k], acc[j][k]);
  }
  // spill y -> LDS bf16: thread covers 32 consecutive ck at row b (4x b128 stores)
  {
    int b = t >> 2, ckb = (t & 3) * 32;
    #pragma unroll
    for (int j = 0; j < 4; j++) {
      ushort4 lo, hi;
      lo.x = f2bf(acc[j][0]); lo.y = f2bf(acc[j][1]); lo.z = f2bf(acc[j][2]); lo.w = f2bf(acc[j][3]);
      hi.x = f2bf(acc[j][4]); hi.y = f2bf(acc[j][5]); hi.z = f2bf(acc[j][6]); hi.w = f2bf(acc[j][7]);
      *(ushort4*)&s_y[b*YLD + ckb + 8*j]     = lo;
      *(ushort4*)&s_y[b*YLD + ckb + 8*j + 4] = hi;
    }
  }
  __syncthreads();

  // stage 2: out[b, n, g] = relu(y[b,:] . gcw[g,:] + gcb[g]) via MFMA 16x16x32 bf16.
  {
    int wv = t >> 6, lane = t & 63;
    int m = lane & 15, q = lane >> 4;
    f32x4 cf0 = {0.f,0.f,0.f,0.f}, cf1 = cf0, cf2 = cf0, cf3 = cf0;
    #pragma unroll
    for (int ks = 0; ks < 4; ks++) {
      bf16x8 a = *(const bf16x8*)&s_y[(16*wv + m)*YLD + 32*ks + 8*q];
      bf16x8 b0 = *(const bf16x8*)&s_gcwB[(m     )*YLD + 32*ks + 8*q];
      bf16x8 b1 = *(const bf16x8*)&s_gcwB[(16 + m)*YLD + 32*ks + 8*q];
      bf16x8 b2 = *(const bf16x8*)&s_gcwB[(32 + m)*YLD + 32*ks + 8*q];
      bf16x8 b3 = *(const bf16x8*)&s_gcwB[(48 + m)*YLD + 32*ks + 8*q];
      cf0 = __builtin_amdgcn_mfma_f32_16x16x32_bf16(a, b0, cf0, 0, 0, 0);
      cf1 = __builtin_amdgcn_mfma_f32_16x16x32_bf16(a, b1, cf1, 0, 0, 0);
      cf2 = __builtin_amdgcn_mfma_f32_16x16x32_bf16(a, b2, cf2, 0, 0, 0);
      cf3 = __builtin_amdgcn_mfma_f32_16x16x32_bf16(a, b3, cf3, 0, 0, 0);
    }
    float* ob = out + (size_t)n*G_;
    #pragma unroll
    for (int r = 0; r < 4; r++) {
      int b = 16*wv + 4*q + r;
      float* op = ob + (size_t)b*(N_*G_);
      float v0 = fmaxf(cf0[r] + s_gcb[m],      0.f);
      float v1 = fmaxf(cf1[r] + s_gcb[16 + m], 0.f);
      float v2 = fmaxf(cf2[r] + s_gcb[32 + m], 0.f);
      float v3 = fmaxf(cf3[r] + s_gcb[48 + m], 0.f);
      op[m]      = v0;
      op[16 + m] = v1;
      op[32 + m] = v2;
      op[48 + m] = v3;
    }
  }
}

extern "C" void kernel_launch(void* const* d_in, const int* in_sizes, int n_in,
                              void* d_out, int out_size, void* d_ws, size_t ws_size,
                              hipStream_t stream) {
  const float* x    = (const float*)d_in[0];
  const float* linc = (const float*)d_in[1];
  const float* rinc = (const float*)d_in[2];
  const float* ef   = (const float*)d_in[3];
  const float* w1   = (const float*)d_in[4];
  const float* b1   = (const float*)d_in[5];
  const float* w2   = (const float*)d_in[6];
  const float* b2   = (const float*)d_in[7];
  const float* gcw  = (const float*)d_in[8];
  const float* gcb  = (const float*)d_in[9];
  float* out = (float*)d_out;

  char* ws = (char*)d_ws;
  float* w_e          = (float*)ws;                 ws += (size_t)E_*K_*sizeof(float);     // 512 KB
  unsigned short* z   = (unsigned short*)ws;        ws += (size_t)E_*BC*sizeof(short);     // 33.5 MB
  unsigned short* x_t = (unsigned short*)ws;        ws += (size_t)N_*BC*sizeof(short);     // 4.2 MB

  xpose_k<<<N_, 256, 0, stream>>>(x, x_t);
  edge_mlp_k<<<E_/256, 256, 0, stream>>>(ef, w1, b1, w2, b2, w_e);
  gather_z_k<<<E_, 256, 0, stream>>>(rinc, x_t, z);
  node_out_k<<<N_, 256, 0, stream>>>(linc, z, w_e, gcw, gcb, out);
}